// Round 6
// baseline (2362.178 us; speedup 1.0000x reference)
//
#include <hip/hip_runtime.h>
#include <cstdint>
#include <cstddef>

#define B_   8
#define N_   2048
#define D_   1024
#define DK_  256
#define M_   (B_ * N_)   // 16384
#define TOPK 32
#define CAP  192
#define QR   16          // q-rows per fused block
#define SCS  2064        // padded LDS score stride (shorts)

typedef unsigned short ushort_t;
typedef float  fvec4 __attribute__((ext_vector_type(4)));
typedef short  bvec8 __attribute__((ext_vector_type(8)));   // 8 bf16 (bits)
typedef float  avec4 __attribute__((ext_vector_type(4)));   // f32 MFMA acc

__device__ inline ushort_t f32_to_bf16_rn(float f) {
  unsigned u = __float_as_uint(f);
  u += 0x7fffu + ((u >> 16) & 1u);     // RNE (no inf/nan in this data)
  return (ushort_t)(u >> 16);
}
__device__ inline float bf16_to_f32(ushort_t u) {
  return __uint_as_float(((unsigned)u) << 16);
}
__device__ inline unsigned bf16_key(ushort_t u) {   // monotone 16-bit key
  return (u & 0x8000u) ? (unsigned)((~u) & 0xFFFFu) : (unsigned)(u | 0x8000u);
}
__device__ inline float key_to_f32(unsigned k) {
  ushort_t u = (k & 0x8000u) ? (ushort_t)(k ^ 0x8000u) : (ushort_t)((~k) & 0xFFFFu);
  return bf16_to_f32(u);
}

// --------------------------------------------------------------------------
// Kernel 1: fused Q/K projection GEMM, f64 accumulation on the VALU.
// 128x128 tile, BK=16, 8x8/thread (proven r5 indexing), now double-buffered
// LDS + register prefetch, ONE barrier per K-tile.
// --------------------------------------------------------------------------
__global__ __launch_bounds__(256, 2) void proj_kernel(
    const float* __restrict__ X, const float* __restrict__ Wq,
    const float* __restrict__ bq, const float* __restrict__ Wk,
    const float* __restrict__ bk, double* __restrict__ Qd,
    double* __restrict__ Kd, ushort_t* __restrict__ Qbf,
    ushort_t* __restrict__ Kbf)
{
  __shared__ float As[2][16][132];   // [buf][k][m]
  __shared__ float Bs[2][16][132];   // [buf][k][j]
  const int tid = threadIdx.x;
  const int tx = tid & 15;           // col-group (8 cols)
  const int ty = tid >> 4;           // row-group (8 rows)
  const int m0 = blockIdx.y * 128;
  const int j0 = blockIdx.x * 128;   // 0,128,256,384
  const bool isQ = (j0 < 256);
  const float* Wp = isQ ? Wq : Wk;
  const float* bp = isQ ? bq : bk;
  const int jw = isQ ? j0 : (j0 - 256);

  const int ar = tid >> 2;           // 0..63 (A row)
  const int ak = (tid & 3) * 4;      // 0,4,8,12 (A k)
  const int bkk = tid >> 4;          // 0..15 (B k)
  const int bj = (tid & 15) * 8;     // 0..120 (B j)

  double acc[8][8];
#pragma unroll
  for (int i = 0; i < 8; i++)
#pragma unroll
    for (int j = 0; j < 8; j++) acc[i][j] = 0.0;

  fvec4 pa0, pa1, pb0, pb1;
  // prologue: load + stage tile 0
  pa0 = *(const fvec4*)&X[(size_t)(m0 + ar) * D_ + ak];
  pa1 = *(const fvec4*)&X[(size_t)(m0 + ar + 64) * D_ + ak];
  pb0 = *(const fvec4*)&Wp[(size_t)bkk * DK_ + jw + bj];
  pb1 = *(const fvec4*)&Wp[(size_t)bkk * DK_ + jw + bj + 4];
#pragma unroll
  for (int c = 0; c < 4; c++) {
    As[0][ak + c][ar] = pa0[c];
    As[0][ak + c][ar + 64] = pa1[c];
  }
  *(fvec4*)&Bs[0][bkk][bj] = pb0;
  *(fvec4*)&Bs[0][bkk][bj + 4] = pb1;
  __syncthreads();

  for (int t = 0; t < 64; ++t) {
    const int cur = t & 1;
    if (t < 63) {   // prefetch tile t+1 into registers
      const int k0 = (t + 1) * 16;
      pa0 = *(const fvec4*)&X[(size_t)(m0 + ar) * D_ + k0 + ak];
      pa1 = *(const fvec4*)&X[(size_t)(m0 + ar + 64) * D_ + k0 + ak];
      pb0 = *(const fvec4*)&Wp[(size_t)(k0 + bkk) * DK_ + jw + bj];
      pb1 = *(const fvec4*)&Wp[(size_t)(k0 + bkk) * DK_ + jw + bj + 4];
    }
#pragma unroll
    for (int kk = 0; kk < 16; kk++) {
      const fvec4 a0 = *(const fvec4*)&As[cur][kk][ty * 8];
      const fvec4 a1 = *(const fvec4*)&As[cur][kk][ty * 8 + 4];
      const fvec4 b0 = *(const fvec4*)&Bs[cur][kk][tx * 8];
      const fvec4 b1 = *(const fvec4*)&Bs[cur][kk][tx * 8 + 4];
      double a[8], b[8];
#pragma unroll
      for (int i = 0; i < 4; i++) {
        a[i] = (double)a0[i]; a[i + 4] = (double)a1[i];
        b[i] = (double)b0[i]; b[i + 4] = (double)b1[i];
      }
#pragma unroll
      for (int i = 0; i < 8; i++)
#pragma unroll
        for (int j = 0; j < 8; j++)
          acc[i][j] = fma(a[i], b[j], acc[i][j]);
    }
    if (t < 63) {   // stage into the other buffer (prev barrier => safe)
      const int nxt = cur ^ 1;
#pragma unroll
      for (int c = 0; c < 4; c++) {
        As[nxt][ak + c][ar] = pa0[c];
        As[nxt][ak + c][ar + 64] = pa1[c];
      }
      *(fvec4*)&Bs[nxt][bkk][bj] = pb0;
      *(fvec4*)&Bs[nxt][bkk][bj + 4] = pb1;
    }
    __syncthreads();
  }

#pragma unroll
  for (int i = 0; i < 8; i++) {
    const int m = m0 + ty * 8 + i;
#pragma unroll
    for (int j = 0; j < 8; j++) {
      const int c = jw + tx * 8 + j;
      const double v = acc[i][j] + (double)bp[c];
      const size_t off = (size_t)m * DK_ + c;
      if (isQ) {
        Qd[off] = v;
        if (Qbf) Qbf[off] = f32_to_bf16_rn((float)v);
      } else {
        Kd[off] = v;
        if (Kbf) Kbf[off] = f32_to_bf16_rn((float)v);
      }
    }
  }
}

// --------------------------------------------------------------------------
// Kernel 2 (fused): per 16 q-rows — bf16 MFMA scores (direct-global frags)
// -> bf16 scores in LDS -> 2-pass radix select -> gather (margin, cap 192)
// -> f64 rescore (identical fma order to r5) -> exact top-32 + softmax
// -> zero-sweep + scatter to out.  Grid: 1024 blocks, bq = bid&7 (XCD-ish).
// --------------------------------------------------------------------------
__global__ __launch_bounds__(256, 2) void fused_score_topk(
    const ushort_t* __restrict__ Qb, const ushort_t* __restrict__ Kb,
    const double* __restrict__ Qd, const double* __restrict__ Kd,
    float* __restrict__ out)
{
  __shared__ __align__(16) unsigned char smem[QR * SCS * 2 + 8192 + 1024 + CAP * 4];
  ushort_t* sc   = (ushort_t*)smem;                         // [QR][SCS] scores
  double*   cval = (double*)smem;                           // [QR][CAP] (reuse, 24.6KB)
  unsigned* histp = (unsigned*)(smem + QR * SCS * 2);       // [8][256] packed
  ushort_t* cidx  = (ushort_t*)(smem + QR * SCS * 2);       // [QR][CAP] (reuse hist)
  unsigned char* tail = smem + QR * SCS * 2 + 8192;
  int*      prefhi = (int*)tail;                // [16]
  int*      want2  = (int*)(tail + 64);         // [16]
  int*      ncand  = (int*)(tail + 128);        // [16]
  unsigned* t32k   = (unsigned*)(tail + 192);   // [16]
  double*   vmaxs  = (double*)(tail + 256);     // [16]
  float*    esums  = (float*)(tail + 448);      // [16]
  float*    evb    = (float*)(tail + 1024);     // [CAP]

  const int tid  = threadIdx.x;
  const int lane = tid & 63;
  const int wid  = tid >> 6;
  const int bid  = blockIdx.x;
  const int bq   = bid & 7;
  const int q0   = (bid >> 3) * QR;
  const size_t rowbase = (size_t)bq * N_;

  // ---- P1: scores GEMM (bf16 MFMA), fragments straight from global ----
  {
    bvec8 aF[8];
#pragma unroll
    for (int ks = 0; ks < 8; ks++)
      aF[ks] = *(const bvec8*)&Qb[(rowbase + q0 + (lane & 15)) * DK_ + ks * 32 + (lane >> 4) * 8];
    const int mw = wid * 512;
    for (int mb = 0; mb < 32; mb++) {
      const int m0 = mw + mb * 16;
      avec4 acc = (avec4)(0.f);
#pragma unroll
      for (int ks = 0; ks < 8; ks++) {
        const bvec8 bF = *(const bvec8*)&Kb[(rowbase + m0 + (lane & 15)) * DK_ + ks * 32 + (lane >> 4) * 8];
        acc = __builtin_amdgcn_mfma_f32_16x16x32_bf16(aF[ks], bF, acc, 0, 0, 0);
      }
#pragma unroll
      for (int i = 0; i < 4; i++) {
        const int r = (lane >> 4) * 4 + i;
        sc[r * SCS + m0 + (lane & 15)] = f32_to_bf16_rn(acc[i] * 0.0625f);
      }
    }
  }
  if (tid < 16) ncand[tid] = 0;
  __syncthreads();

  // ---- P2: 2-pass radix select of 32nd-largest per row (bf16 keys) ----
  const int r16 = tid >> 4;         // my row for hist passes
  const int c16 = tid & 15;
  const unsigned inc = (r16 & 1) ? 0x10000u : 1u;
  const int pr = r16 >> 1;

  // pass 1: high byte
#pragma unroll
  for (int z = 0; z < 8; z++) histp[z * 256 + tid] = 0u;
  __syncthreads();
  for (int j = 0; j < 128; j++) {
    const unsigned key = bf16_key(sc[r16 * SCS + c16 + j * 16]);
    atomicAdd(&histp[pr * 256 + (key >> 8)], inc);
  }
  __syncthreads();
  for (int st = 1; st < 256; st <<= 1) {
    unsigned add[8];
#pragma unroll
    for (int p = 0; p < 8; p++)
      add[p] = (tid + st < 256) ? histp[p * 256 + tid + st] : 0u;
    __syncthreads();
#pragma unroll
    for (int p = 0; p < 8; p++) histp[p * 256 + tid] += add[p];
    __syncthreads();
  }
  for (int r = 0; r < QR; r++) {
    const unsigned w0 = histp[(r >> 1) * 256 + tid];
    const unsigned w1 = (tid == 255) ? 0u : histp[(r >> 1) * 256 + tid + 1];
    const int s_b  = (r & 1) ? (int)(w0 >> 16) : (int)(w0 & 0xFFFFu);
    const int s_b1 = (r & 1) ? (int)(w1 >> 16) : (int)(w1 & 0xFFFFu);
    if (s_b >= TOPK && s_b1 < TOPK) { prefhi[r] = tid; want2[r] = TOPK - s_b1; }
  }
  __syncthreads();

  // pass 2: low byte among entries with matching high byte
#pragma unroll
  for (int z = 0; z < 8; z++) histp[z * 256 + tid] = 0u;
  __syncthreads();
  {
    const unsigned ph = (unsigned)prefhi[r16];
    for (int j = 0; j < 128; j++) {
      const unsigned key = bf16_key(sc[r16 * SCS + c16 + j * 16]);
      if ((key >> 8) == ph) atomicAdd(&histp[pr * 256 + (key & 255u)], inc);
    }
  }
  __syncthreads();
  for (int st = 1; st < 256; st <<= 1) {
    unsigned add[8];
#pragma unroll
    for (int p = 0; p < 8; p++)
      add[p] = (tid + st < 256) ? histp[p * 256 + tid + st] : 0u;
    __syncthreads();
#pragma unroll
    for (int p = 0; p < 8; p++) histp[p * 256 + tid] += add[p];
    __syncthreads();
  }
  for (int r = 0; r < QR; r++) {
    const unsigned w0 = histp[(r >> 1) * 256 + tid];
    const unsigned w1 = (tid == 255) ? 0u : histp[(r >> 1) * 256 + tid + 1];
    const int s_b  = (r & 1) ? (int)(w0 >> 16) : (int)(w0 & 0xFFFFu);
    const int s_b1 = (r & 1) ? (int)(w1 >> 16) : (int)(w1 & 0xFFFFu);
    const int w = want2[r];
    if (s_b >= w && s_b1 < w)
      t32k[r] = ((unsigned)prefhi[r] << 8) | (unsigned)tid;
  }
  __syncthreads();

  // ---- gather candidates (writes cidx into the dead hist region) ----
  {
    const float cthr = key_to_f32(t32k[r16]) - 1.6e-2f;
    for (int j = 0; j < 128; j++) {
      const int c = c16 + j * 16;
      const float v = bf16_to_f32(sc[r16 * SCS + c]);
      if (v >= cthr) {
        const int p = atomicAdd(&ncand[r16], 1);
        if (p < CAP) cidx[r16 * CAP + p] = (ushort_t)c;
      }
    }
  }
  __syncthreads();

  // ---- P3: zero-sweep output rows (drains under later barriers) ----
  {
    float* orow = out + (rowbase + q0) * N_;
    fvec4 z = (fvec4)(0.f);
    for (int i = tid; i < QR * N_ / 4; i += 256)
      *(fvec4*)&orow[i * 4] = z;
  }

  // ---- P4: f64 rescore (sc region is dead; cval overlays it) ----
  for (int rr = wid; rr < QR; rr += 4) {
    const int ncr = min(ncand[rr], CAP);
    const double* qp = Qd + (rowbase + q0 + rr) * DK_;
    for (int c = 0; c < ncr; c++) {
      const double* kp = Kd + (rowbase + cidx[rr * CAP + c]) * DK_;
      double a = 0.0;
#pragma unroll
      for (int q = 0; q < 4; q++)
        a = fma(qp[lane * 4 + q], kp[lane * 4 + q], a);
#pragma unroll
      for (int off = 32; off > 0; off >>= 1) a += __shfl_xor(a, off);
      if (lane == 0) cval[rr * CAP + c] = a * 0.0625;
    }
  }
  __syncthreads();

  // ---- P5: exact top-32 (value desc, idx asc) + softmax + scatter ----
  for (int r = 0; r < QR; r++) {
    const int ncr = min(ncand[r], CAP);
    bool sel = false;
    double v = 0.0;
    int myidx = 0;
    if (tid < ncr) {
      v = cval[r * CAP + tid];
      myidx = (int)cidx[r * CAP + tid];
      int rank = 0;
      for (int j = 0; j < ncr; j++) {
        const double vj = cval[r * CAP + j];
        rank += (vj > v) || (vj == v && (int)cidx[r * CAP + j] < myidx);
      }
      sel = (rank < TOPK);
    }
    if (tid == 0) {
      double mx = cval[r * CAP];
      for (int j = 1; j < ncr; j++) mx = cval[r * CAP + j] > mx ? cval[r * CAP + j] : mx;
      vmaxs[r] = mx;
    }
    __syncthreads();
    const float ev = sel ? expf((float)(v - vmaxs[r])) : 0.f;
    if (tid < ncr) evb[tid] = ev;
    __syncthreads();
    if (tid == 0) {
      float ssum = 0.f;
      for (int j = 0; j < ncr; j++) ssum += evb[j];
      esums[r] = ssum;
    }
    __syncthreads();
    if (sel) out[(rowbase + q0 + r) * N_ + myidx] = ev / esums[r];
    __syncthreads();
  }
}

// --------------------------------------------------------------------------
// Fallback kernels (ws too small for bf16 copies): proven r5 path.
// --------------------------------------------------------------------------
__global__ __launch_bounds__(256) void score_f64_kernel(
    const double* __restrict__ Qd, const double* __restrict__ Kd,
    float* __restrict__ out)
{
  __shared__ float As[16][68];
  __shared__ float Bs[16][68];
  const int tid = threadIdx.x;
  const int tx = tid & 15, ty = tid >> 4;
  const int b  = blockIdx.z;
  const int q0 = blockIdx.y * 64;
  const int m0 = blockIdx.x * 64;
  const size_t rowbase = (size_t)b * N_;

  float acc[4][4];
#pragma unroll
  for (int i = 0; i < 4; i++)
#pragma unroll
    for (int j = 0; j < 4; j++) acc[i][j] = 0.f;

  for (int k0 = 0; k0 < DK_; k0 += 16) {
    const int mt = tid >> 4, kt = tid & 15;
#pragma unroll
    for (int p = 0; p < 4; p++) {
      const int m = mt + 16 * p;
      As[kt][m] = (float)Qd[(rowbase + q0 + m) * DK_ + k0 + kt];
      Bs[kt][m] = (float)Kd[(rowbase + m0 + m) * DK_ + k0 + kt];
    }
    __syncthreads();
#pragma unroll
    for (int kk = 0; kk < 16; kk++) {
      float a[4], bb[4];
#pragma unroll
      for (int i = 0; i < 4; i++) a[i] = As[kk][ty * 4 + i];
#pragma unroll
      for (int j = 0; j < 4; j++) bb[j] = Bs[kk][tx * 4 + j];
#pragma unroll
      for (int i = 0; i < 4; i++)
#pragma unroll
        for (int j = 0; j < 4; j++)
          acc[i][j] = fmaf(a[i], bb[j], acc[i][j]);
    }
    __syncthreads();
  }

#pragma unroll
  for (int i = 0; i < 4; i++) {
    const size_t r = (size_t)b * N_ + q0 + ty * 4 + i;
#pragma unroll
    for (int j = 0; j < 4; j++)
      out[r * N_ + m0 + tx * 4 + j] = acc[i][j] * 0.0625f;
  }
}

__global__ __launch_bounds__(256) void topk_softmax_kernel(
    float* __restrict__ out, const double* __restrict__ Qd,
    const double* __restrict__ Kd, float margin)
{
  const int row = blockIdx.x;
  const int b   = row >> 11;
  const int tid = threadIdx.x;
  float* rowp = out + (size_t)row * N_;

  __shared__ float    s[N_];
  __shared__ double   qrow[DK_];
  __shared__ unsigned hist[256];
  __shared__ unsigned sfx[256];
  __shared__ int      cidx[128];
  __shared__ double   cval[128];
  __shared__ float    ceval[128];
  __shared__ int      ncand_s;
  __shared__ unsigned prefix_s;
  __shared__ int      want_s;
  __shared__ double   vmax_s;
  __shared__ float    esum_s;

  for (int i = tid; i < N_; i += 256) s[i] = rowp[i];
  qrow[tid] = Qd[(size_t)row * DK_ + tid];
  __syncthreads();

  unsigned prefix = 0;
  int want = TOPK;
  for (int pass = 0; pass < 4; pass++) {
    hist[tid] = 0;
    __syncthreads();
    const int shift_b = 24 - 8 * pass;
    for (int i = tid; i < N_; i += 256) {
      unsigned u = __float_as_uint(s[i]);
      u = (u & 0x80000000u) ? ~u : (u | 0x80000000u);
      const bool ok = (pass == 0) || ((u >> (shift_b + 8)) == prefix);
      if (ok) atomicAdd(&hist[(u >> shift_b) & 255u], 1u);
    }
    __syncthreads();
    sfx[tid] = hist[tid];
    __syncthreads();
    for (int st = 1; st < 256; st <<= 1) {
      const unsigned add = (tid + st < 256) ? sfx[tid + st] : 0u;
      __syncthreads();
      sfx[tid] += add;
      __syncthreads();
    }
    const int gt = (int)(sfx[tid] - hist[tid]);
    if (gt < want && (int)sfx[tid] >= want) {
      prefix_s = (prefix << 8) | (unsigned)tid;
      want_s = want - gt;
    }
    __syncthreads();
    prefix = prefix_s;
    want = want_s;
    __syncthreads();
  }
  const unsigned su = prefix;
  const unsigned uu = (su & 0x80000000u) ? (su ^ 0x80000000u) : ~su;
  const float t32 = __uint_as_float(uu);
  const float cthr = t32 - margin;

  if (tid == 0) ncand_s = 0;
  __syncthreads();
  for (int i = tid; i < N_; i += 256) {
    if (s[i] >= cthr) {
      const int p = atomicAdd(&ncand_s, 1);
      if (p < 128) cidx[p] = i;
    }
  }
  __syncthreads();
  int nc = ncand_s;
  if (nc > 128) nc = 128;

  const int wid = tid >> 6, lane = tid & 63;
  for (int base = 0; base < nc; base += 4) {
    const int c = base + wid;
    if (c < nc) {
      const double* kp = Kd + ((size_t)b * N_ + cidx[c]) * DK_;
      double a = 0.0;
#pragma unroll
      for (int q = 0; q < 4; q++)
        a = fma(qrow[lane * 4 + q], kp[lane * 4 + q], a);
#pragma unroll
      for (int off = 32; off > 0; off >>= 1) a += __shfl_xor(a, off);
      if (lane == 0) cval[c] = a * 0.0625;
    }
  }
  __syncthreads();

  bool sel = false;
  double v = 0.0;
  int myidx = 0;
  if (tid < nc) {
    v = cval[tid];
    myidx = cidx[tid];
    int rank = 0;
    for (int j = 0; j < nc; j++) {
      const double vj = cval[j];
      rank += (vj > v) || (vj == v && cidx[j] < myidx);
    }
    sel = (rank < TOPK);
  }
  if (tid == 0) {
    double mx = cval[0];
    for (int j = 1; j < nc; j++) mx = cval[j] > mx ? cval[j] : mx;
    vmax_s = mx;
  }
  __syncthreads();
  const float ev = sel ? expf((float)(v - vmax_s)) : 0.f;
  if (tid < 128) ceval[tid] = ev;
  __syncthreads();
  if (tid == 0) {
    float ssum = 0.f;
    for (int j = 0; j < nc; j++) ssum += ceval[j];
    esum_s = ssum;
  }
  __syncthreads();

  for (int i = tid; i < N_; i += 256) s[i] = 0.f;
  __syncthreads();
  if (tid < nc && sel) s[myidx] = ev / esum_s;
  __syncthreads();
  for (int i = tid; i < N_; i += 256) rowp[i] = s[i];
}

// --------------------------------------------------------------------------
extern "C" void kernel_launch(void* const* d_in, const int* in_sizes, int n_in,
                              void* d_out, int out_size, void* d_ws,
                              size_t ws_size, hipStream_t stream)
{
  const float* X  = (const float*)d_in[0];
  const float* Wq = (const float*)d_in[1];
  const float* bq = (const float*)d_in[2];
  const float* Wk = (const float*)d_in[3];
  const float* bk = (const float*)d_in[4];
  float* out = (float*)d_out;

  const size_t qk = (size_t)M_ * DK_;
  const size_t f64_bytes = qk * sizeof(double) * 2;           // 67.1 MB
  const size_t bf_bytes  = qk * sizeof(ushort_t) * 2;         // 16.8 MB
  if (ws_size < f64_bytes) return;
  const bool bfpath = (ws_size >= f64_bytes + bf_bytes);

  double* Qd = (double*)d_ws;
  double* Kd = Qd + qk;
  ushort_t* Qbf = (ushort_t*)(Kd + qk);
  ushort_t* Kbf = Qbf + qk;

  dim3 blk(256);
  proj_kernel<<<dim3(4, 128), blk, 0, stream>>>(
      X, Wq, bq, Wk, bk, Qd, Kd, bfpath ? Qbf : (ushort_t*)nullptr,
      bfpath ? Kbf : (ushort_t*)nullptr);

  if (bfpath) {
    fused_score_topk<<<dim3(M_ / QR), blk, 0, stream>>>(Qbf, Kbf, Qd, Kd, out);
  } else {
    score_f64_kernel<<<dim3(N_ / 64, N_ / 64, B_), blk, 0, stream>>>(Qd, Kd, out);
    topk_softmax_kernel<<<dim3(M_), blk, 0, stream>>>(out, Qd, Kd, 2.5e-4f);
  }
}

// Round 7
// 682.817 us; speedup vs baseline: 3.4595x; 3.4595x over previous
//
#include <hip/hip_runtime.h>
#include <cstdint>
#include <cstddef>

#define B_   8
#define N_   2048
#define D_   1024
#define DK_  256
#define M_   (B_ * N_)   // 16384
#define TOPK 32

typedef unsigned short ushort_t;
typedef float  fvec4 __attribute__((ext_vector_type(4)));
typedef short  bvec8 __attribute__((ext_vector_type(8)));   // 8 bf16 (bits)
typedef float  avec4 __attribute__((ext_vector_type(4)));   // f32 MFMA acc
typedef int    ivec4 __attribute__((ext_vector_type(4)));   // 16B staging

__device__ inline ushort_t f32_to_bf16_rn(float f) {
  unsigned u = __float_as_uint(f);
  u += 0x7fffu + ((u >> 16) & 1u);     // RNE (no inf/nan in this data)
  return (ushort_t)(u >> 16);
}

// --------------------------------------------------------------------------
// Kernel 1: fused Q/K projection GEMM, f64 accumulation on the VALU.
// Tile 128(m) x 64(j), BK=16, 8x4 per thread (acc = 64 VGPR -> ~4 waves/SIMD
// for latency hiding). LDS in f32; cvt to f64 at fragment load.
// Single-buffered, 2 barriers/tile (proven r5 structure, smaller tile).
// --------------------------------------------------------------------------
__global__ __launch_bounds__(256) void proj_kernel(
    const float* __restrict__ X, const float* __restrict__ Wq,
    const float* __restrict__ bq, const float* __restrict__ Wk,
    const float* __restrict__ bk, double* __restrict__ Qd,
    double* __restrict__ Kd, ushort_t* __restrict__ Qbf,
    ushort_t* __restrict__ Kbf)
{
  __shared__ float As[16][132];   // [k][m], pad 132 (528B rows)
  __shared__ float Bs[16][68];    // [k][j], pad 68 (272B rows)
  const int tid = threadIdx.x;
  const int tx = tid & 15;        // col-group (4 cols)
  const int ty = tid >> 4;        // row-group (8 rows)
  const int m0 = blockIdx.y * 128;
  const int j0 = blockIdx.x * 64;          // 0..448
  const bool isQ = (j0 < 256);
  const float* Wp = isQ ? Wq : Wk;
  const float* bp = isQ ? bq : bk;
  const int jw = isQ ? j0 : (j0 - 256);

  const int ar = tid >> 2;           // 0..63 (A row)
  const int ak = (tid & 3) * 4;      // 0,4,8,12 (A k)
  const int bkk = tid >> 4;          // 0..15 (B k)
  const int bj = (tid & 15) * 4;     // 0..60 (B j)

  double acc[8][4];
#pragma unroll
  for (int i = 0; i < 8; i++)
#pragma unroll
    for (int j = 0; j < 4; j++) acc[i][j] = 0.0;

  for (int k0 = 0; k0 < D_; k0 += 16) {
    {  // A tile: 128 rows x 16 k -> transposed As[k][m]. 2 fvec4 per thread.
#pragma unroll
      for (int p = 0; p < 2; p++) {
        const int m = ar + 64 * p;
        const fvec4 v = *(const fvec4*)&X[(size_t)(m0 + m) * D_ + k0 + ak];
#pragma unroll
        for (int c = 0; c < 4; c++) As[ak + c][m] = v[c];
      }
    }
    {  // B tile: 16 k x 64 j, straight copy. 1 fvec4 per thread.
      *(fvec4*)&Bs[bkk][bj] =
          *(const fvec4*)&Wp[(size_t)(k0 + bkk) * DK_ + jw + bj];
    }
    __syncthreads();
#pragma unroll
    for (int kk = 0; kk < 16; kk++) {
      const fvec4 a0 = *(const fvec4*)&As[kk][ty * 8];
      const fvec4 a1 = *(const fvec4*)&As[kk][ty * 8 + 4];
      const fvec4 b0 = *(const fvec4*)&Bs[kk][tx * 4];
      double a[8], b[4];
#pragma unroll
      for (int i = 0; i < 4; i++) {
        a[i] = (double)a0[i]; a[i + 4] = (double)a1[i];
        b[i] = (double)b0[i];
      }
#pragma unroll
      for (int i = 0; i < 8; i++)
#pragma unroll
        for (int j = 0; j < 4; j++)
          acc[i][j] = fma(a[i], b[j], acc[i][j]);
    }
    __syncthreads();
  }

#pragma unroll
  for (int i = 0; i < 8; i++) {
    const int m = m0 + ty * 8 + i;
#pragma unroll
    for (int j = 0; j < 4; j++) {
      const int c = jw + tx * 4 + j;
      const double v = acc[i][j] + (double)bp[c];
      const size_t off = (size_t)m * DK_ + c;
      if (isQ) {
        Qd[off] = v;
        if (Qbf) Qbf[off] = f32_to_bf16_rn((float)v);
      } else {
        Kd[off] = v;
        if (Kbf) Kbf[off] = f32_to_bf16_rn((float)v);
      }
    }
  }
}

// --------------------------------------------------------------------------
// Kernel 2a: scores via bf16 MFMA 16x16x32 (candidate precision only).
// Proven r2/r5 kernel, unchanged.
// --------------------------------------------------------------------------
__global__ __launch_bounds__(256) void score_bf16_kernel(
    const ushort_t* __restrict__ Qb, const ushort_t* __restrict__ Kb,
    float* __restrict__ out)
{
  __shared__ ushort_t Asl[128 * 40];
  __shared__ ushort_t Bsl[128 * 40];
  const int tid = threadIdx.x;
  const int b  = blockIdx.z;
  const int q0 = blockIdx.y * 128;
  const int m0 = blockIdx.x * 128;
  const int w = tid >> 6, lane = tid & 63;
  const int wq = (w >> 1) * 64, wm = (w & 1) * 64;
  const int rsel = lane & 15, ksel = (lane >> 4) * 8;

  avec4 acc[4][4];
#pragma unroll
  for (int i = 0; i < 4; i++)
#pragma unroll
    for (int j = 0; j < 4; j++) acc[i][j] = (avec4)(0.f);

  for (int k0 = 0; k0 < DK_; k0 += 32) {
#pragma unroll
    for (int cc = 0; cc < 2; cc++) {
      const int c = tid + cc * 256;
      const int r = c >> 2, part = c & 3;
      const ivec4 va = *(const ivec4*)&Qb[((size_t)b * N_ + q0 + r) * DK_ + k0 + part * 8];
      const ivec4 vb = *(const ivec4*)&Kb[((size_t)b * N_ + m0 + r) * DK_ + k0 + part * 8];
      *(ivec4*)&Asl[r * 40 + part * 8] = va;
      *(ivec4*)&Bsl[r * 40 + part * 8] = vb;
    }
    __syncthreads();
    bvec8 aF[4], bF[4];
#pragma unroll
    for (int mi = 0; mi < 4; mi++)
      aF[mi] = *(const bvec8*)&Asl[(wq + mi * 16 + rsel) * 40 + ksel];
#pragma unroll
    for (int nj = 0; nj < 4; nj++)
      bF[nj] = *(const bvec8*)&Bsl[(wm + nj * 16 + rsel) * 40 + ksel];
#pragma unroll
    for (int mi = 0; mi < 4; mi++)
#pragma unroll
      for (int nj = 0; nj < 4; nj++)
        acc[mi][nj] = __builtin_amdgcn_mfma_f32_16x16x32_bf16(
            aF[mi], bF[nj], acc[mi][nj], 0, 0, 0);
    __syncthreads();
  }

#pragma unroll
  for (int mi = 0; mi < 4; mi++)
#pragma unroll
    for (int nj = 0; nj < 4; nj++)
#pragma unroll
      for (int r = 0; r < 4; r++) {
        const int row = q0 + wq + mi * 16 + (lane >> 4) * 4 + r;
        const int col = m0 + wm + nj * 16 + (lane & 15);
        out[((size_t)b * N_ + row) * N_ + col] = acc[mi][nj][r] * 0.0625f;
      }
}

// --------------------------------------------------------------------------
// Kernel 2b (fallback if ws too small for bf16 copies): f32 scores from f64.
// --------------------------------------------------------------------------
__global__ __launch_bounds__(256) void score_f64_kernel(
    const double* __restrict__ Qd, const double* __restrict__ Kd,
    float* __restrict__ out)
{
  __shared__ float As[16][68];
  __shared__ float Bs[16][68];
  const int tid = threadIdx.x;
  const int tx = tid & 15, ty = tid >> 4;
  const int b  = blockIdx.z;
  const int q0 = blockIdx.y * 64;
  const int m0 = blockIdx.x * 64;
  const size_t rowbase = (size_t)b * N_;

  float acc[4][4];
#pragma unroll
  for (int i = 0; i < 4; i++)
#pragma unroll
    for (int j = 0; j < 4; j++) acc[i][j] = 0.f;

  for (int k0 = 0; k0 < DK_; k0 += 16) {
    const int mt = tid >> 4, kt = tid & 15;
#pragma unroll
    for (int p = 0; p < 4; p++) {
      const int m = mt + 16 * p;
      As[kt][m] = (float)Qd[(rowbase + q0 + m) * DK_ + k0 + kt];
      Bs[kt][m] = (float)Kd[(rowbase + m0 + m) * DK_ + k0 + kt];
    }
    __syncthreads();
#pragma unroll
    for (int kk = 0; kk < 16; kk++) {
      float a[4], bb[4];
#pragma unroll
      for (int i = 0; i < 4; i++) a[i] = As[kk][ty * 4 + i];
#pragma unroll
      for (int j = 0; j < 4; j++) bb[j] = Bs[kk][tx * 4 + j];
#pragma unroll
      for (int i = 0; i < 4; i++)
#pragma unroll
        for (int j = 0; j < 4; j++)
          acc[i][j] = fmaf(a[i], bb[j], acc[i][j]);
    }
    __syncthreads();
  }

#pragma unroll
  for (int i = 0; i < 4; i++) {
    const size_t r = (size_t)b * N_ + q0 + ty * 4 + i;
#pragma unroll
    for (int j = 0; j < 4; j++)
      out[r * N_ + m0 + tx * 4 + j] = acc[i][j] * 0.0625f;
  }
}

// --------------------------------------------------------------------------
// Kernel 3: per-row exact top-32 (radix select with margin + f64 rescore)
// and softmax. One block (256 threads) per row. Proven r5 kernel, unchanged.
// --------------------------------------------------------------------------
__global__ __launch_bounds__(256) void topk_softmax_kernel(
    float* __restrict__ out, const double* __restrict__ Qd,
    const double* __restrict__ Kd, float margin)
{
  const int row = blockIdx.x;
  const int b   = row >> 11;
  const int tid = threadIdx.x;
  float* rowp = out + (size_t)row * N_;

  __shared__ float    s[N_];
  __shared__ double   qrow[DK_];
  __shared__ unsigned hist[256];
  __shared__ unsigned sfx[256];
  __shared__ int      cidx[128];
  __shared__ double   cval[128];
  __shared__ float    ceval[128];
  __shared__ int      ncand_s;
  __shared__ unsigned prefix_s;
  __shared__ int      want_s;
  __shared__ double   vmax_s;
  __shared__ float    esum_s;

  for (int i = tid; i < N_; i += 256) s[i] = rowp[i];
  qrow[tid] = Qd[(size_t)row * DK_ + tid];
  __syncthreads();

  unsigned prefix = 0;
  int want = TOPK;
  for (int pass = 0; pass < 4; pass++) {
    hist[tid] = 0;
    __syncthreads();
    const int shift_b = 24 - 8 * pass;
    for (int i = tid; i < N_; i += 256) {
      unsigned u = __float_as_uint(s[i]);
      u = (u & 0x80000000u) ? ~u : (u | 0x80000000u);
      const bool ok = (pass == 0) || ((u >> (shift_b + 8)) == prefix);
      if (ok) atomicAdd(&hist[(u >> shift_b) & 255u], 1u);
    }
    __syncthreads();
    sfx[tid] = hist[tid];
    __syncthreads();
    for (int st = 1; st < 256; st <<= 1) {
      const unsigned add = (tid + st < 256) ? sfx[tid + st] : 0u;
      __syncthreads();
      sfx[tid] += add;
      __syncthreads();
    }
    const int gt = (int)(sfx[tid] - hist[tid]);
    if (gt < want && (int)sfx[tid] >= want) {
      prefix_s = (prefix << 8) | (unsigned)tid;
      want_s = want - gt;
    }
    __syncthreads();
    prefix = prefix_s;
    want = want_s;
    __syncthreads();
  }
  const unsigned su = prefix;
  const unsigned uu = (su & 0x80000000u) ? (su ^ 0x80000000u) : ~su;
  const float t32 = __uint_as_float(uu);
  const float cthr = t32 - margin;

  if (tid == 0) ncand_s = 0;
  __syncthreads();
  for (int i = tid; i < N_; i += 256) {
    if (s[i] >= cthr) {
      const int p = atomicAdd(&ncand_s, 1);
      if (p < 128) cidx[p] = i;
    }
  }
  __syncthreads();
  int nc = ncand_s;
  if (nc > 128) nc = 128;

  const int wid = tid >> 6, lane = tid & 63;
  for (int base = 0; base < nc; base += 4) {
    const int c = base + wid;
    if (c < nc) {
      const double* kp = Kd + ((size_t)b * N_ + cidx[c]) * DK_;
      double a = 0.0;
#pragma unroll
      for (int q = 0; q < 4; q++)
        a = fma(qrow[lane * 4 + q], kp[lane * 4 + q], a);
#pragma unroll
      for (int off = 32; off > 0; off >>= 1) a += __shfl_xor(a, off);
      if (lane == 0) cval[c] = a * 0.0625;
    }
  }
  __syncthreads();

  bool sel = false;
  double v = 0.0;
  int myidx = 0;
  if (tid < nc) {
    v = cval[tid];
    myidx = cidx[tid];
    int rank = 0;
    for (int j = 0; j < nc; j++) {
      const double vj = cval[j];
      rank += (vj > v) || (vj == v && cidx[j] < myidx);
    }
    sel = (rank < TOPK);
  }
  if (tid == 0) {
    double mx = cval[0];
    for (int j = 1; j < nc; j++) mx = cval[j] > mx ? cval[j] : mx;
    vmax_s = mx;
  }
  __syncthreads();
  const float ev = sel ? expf((float)(v - vmax_s)) : 0.f;
  if (tid < 128) ceval[tid] = ev;
  __syncthreads();
  if (tid == 0) {
    float ssum = 0.f;
    for (int j = 0; j < nc; j++) ssum += ceval[j];
    esum_s = ssum;
  }
  __syncthreads();

  for (int i = tid; i < N_; i += 256) s[i] = 0.f;
  __syncthreads();
  if (tid < nc && sel) s[myidx] = ev / esum_s;
  __syncthreads();
  for (int i = tid; i < N_; i += 256) rowp[i] = s[i];
}

// --------------------------------------------------------------------------
extern "C" void kernel_launch(void* const* d_in, const int* in_sizes, int n_in,
                              void* d_out, int out_size, void* d_ws,
                              size_t ws_size, hipStream_t stream)
{
  const float* X  = (const float*)d_in[0];
  const float* Wq = (const float*)d_in[1];
  const float* bq = (const float*)d_in[2];
  const float* Wk = (const float*)d_in[3];
  const float* bk = (const float*)d_in[4];
  float* out = (float*)d_out;

  const size_t qk = (size_t)M_ * DK_;
  const size_t f64_bytes = qk * sizeof(double) * 2;           // 67.1 MB
  const size_t bf_bytes  = qk * sizeof(ushort_t) * 2;         // 16.8 MB
  if (ws_size < f64_bytes) return;
  const bool bfpath = (ws_size >= f64_bytes + bf_bytes);

  double* Qd = (double*)d_ws;
  double* Kd = Qd + qk;
  ushort_t* Qbf = (ushort_t*)(Kd + qk);
  ushort_t* Kbf = Qbf + qk;

  dim3 blk(256);
  proj_kernel<<<dim3(8, 128), blk, 0, stream>>>(
      X, Wq, bq, Wk, bk, Qd, Kd, bfpath ? Qbf : (ushort_t*)nullptr,
      bfpath ? Kbf : (ushort_t*)nullptr);

  float margin;
  if (bfpath) {
    score_bf16_kernel<<<dim3(N_ / 128, N_ / 128, B_), blk, 0, stream>>>(Qbf, Kbf, out);
    margin = 8e-3f;
  } else {
    score_f64_kernel<<<dim3(N_ / 64, N_ / 64, B_), blk, 0, stream>>>(Qd, Kd, out);
    margin = 2.5e-4f;
  }

  topk_softmax_kernel<<<dim3(M_), blk, 0, stream>>>(out, Qd, Kd, margin);
}